// Round 11
// baseline (69.565 us; speedup 1.0000x reference)
//
#include <hip/hip_runtime.h>
#include <hip/hip_bf16.h>
#include <stdint.h>

// PositionalSAE on MI355X — round 11.
// Cooperative-staged GEMMs (BN=128): W tile rows staged as 512-B contiguous
// spans (2 rows per gload_lds16), 3 LDS buffers, counted vmcnt(4) kept across
// a single s_barrier per step (never drains in steady state). Waves split n
// (no cross-wave reduce). Deeper k-split -> bf16 partials (8 enc / 16 dec).

#define D_IN   2048
#define CHUNK  4096
#define RS     32
#define LN_EPS 1e-5f

typedef __attribute__((ext_vector_type(8))) short bf16x8;
typedef __attribute__((ext_vector_type(4))) short bf16x4;
typedef __attribute__((ext_vector_type(4))) float f32x4;

#define AS1 __attribute__((address_space(1)))
#define AS3 __attribute__((address_space(3)))

__device__ __forceinline__ void gload_lds16(const float* g, float* l) {
  __builtin_amdgcn_global_load_lds((const AS1 unsigned int*)g,
                                   (AS3 unsigned int*)l, 16, 0, 0);
}

__device__ __forceinline__ unsigned short f2bf(float f) {
  unsigned int u = __float_as_uint(f);
  u += 0x7fffu + ((u >> 16) & 1u);
  return (unsigned short)(u >> 16);
}
__device__ __forceinline__ float bf2f(unsigned short s) {
  return __uint_as_float(((unsigned int)s) << 16);
}

#define MFMA16 __builtin_amdgcn_mfma_f32_16x16x32_bf16

// ---------------------------------------------------------------------------
// Kernel 1: prep. xfrag[r][mt][kt(64)][lane(64)][8] bf16, MFMA A-frag order:
//   element j = x[m = mt*16 + (lane&15)][k = kt*32 + (lane>>4)*8 + j]
// x = acts + pos_emb[r] - b_dec.
// ---------------------------------------------------------------------------
__global__ __launch_bounds__(256) void prep_kernel(
    const float* __restrict__ acts, const float* __restrict__ pos,
    const float* __restrict__ bdec, unsigned short* __restrict__ xfrag) {
  unsigned tid = blockIdx.x * 256u + threadIdx.x;
  unsigned lane = tid & 63u, kt = (tid >> 6) & 63u, mt = (tid >> 12) & 1u, r = tid >> 13;
  unsigned m  = mt * 16 + (lane & 15u);
  unsigned k0 = kt * 32 + (lane >> 4) * 8;
  const float* ap = acts + (size_t)(r * RS + m) * D_IN + k0;
  const float* pp = pos  + (size_t)r * D_IN + k0;
  const float* bp = bdec + k0;
  bf16x8 v;
#pragma unroll
  for (int j = 0; j < 8; ++j) v[j] = (short)f2bf(ap[j] + pp[j] - bp[j]);
  *reinterpret_cast<bf16x8*>(xfrag + (size_t)tid * 8) = v;
}

// ---------------------------------------------------------------------------
// Kernel 2: encoder. grid = 4r x 8h x 32nt = 1024 blocks, 256 thr (4 waves).
// Block tile 32m x 128n, K' = 256 (8 steps of 32 k-rows). Waves split n
// (wave w owns cols [w*32,+32)). Cooperative 512B-contiguous staging into 3
// LDS buffers; counted vmcnt(4) across one s_barrier per step.
// Writes bf16 partial h of pre.
// ---------------------------------------------------------------------------
__global__ __launch_bounds__(256) void enc_kernel(
    const unsigned short* __restrict__ xfrag, const float* __restrict__ Wenc,
    unsigned short* __restrict__ pre_part) {
  const unsigned r = blockIdx.x >> 8;
  const unsigned h = (blockIdx.x >> 5) & 7u;
  const unsigned nt = blockIdx.x & 31u;
  const unsigned n0 = nt * 128;
  const unsigned w = threadIdx.x >> 6, lane = threadIdx.x & 63u;
  const unsigned col = lane & 15u, g = lane >> 4;

  __shared__ float tiles[3][32 * 128];          // 48 KiB

  // staging: wave w covers tile rows [w*8, w*8+8); each gload = 2 rows x 512B
  const unsigned srow = w * 8 + (lane >> 5);
  const unsigned scol = (lane & 31u) * 4u;
  const float* gbase = Wenc + ((size_t)(r * D_IN + h * 256 + srow)) * CHUNK + n0 + scol;
  const unsigned short* xa0 = xfrag + ((size_t)(r * 2 + 0) * 64) * 512 + (size_t)lane * 8;
  const unsigned short* xa1 = xfrag + ((size_t)(r * 2 + 1) * 64) * 512 + (size_t)lane * 8;

  f32x4 acc00 = {0.f,0.f,0.f,0.f}, acc01 = acc00, acc10 = acc00, acc11 = acc00;

  auto stageW = [&](int s, int b) {
#pragma unroll
    for (int l = 0; l < 4; ++l) {
      const float* gp = gbase + (size_t)(s * 32 + 2 * l) * CHUNK;
      gload_lds16(gp, &tiles[b][(w * 8 + 2 * l) * 128]);
    }
  };
  auto loadA = [&](int s, bf16x8& A0, bf16x8& A1) {
    unsigned kt = h * 8 + (unsigned)s;
    A0 = *(const bf16x8*)(xa0 + (size_t)kt * 512);
    A1 = *(const bf16x8*)(xa1 + (size_t)kt * 512);
  };

  bf16x8 aC0, aC1, aN0, aN1;
  stageW(0, 0);            // 4 vmem (oldest)
  loadA(0, aC0, aC1);      // 2 vmem
  stageW(1, 1);            // 4 vmem (newest)

#pragma unroll
  for (int s = 0; s < 8; ++s) {
    // retire stage(s)+A(s); keep stage(s+1) in flight across the barrier
    if (s < 7) asm volatile("s_waitcnt vmcnt(4)" ::: "memory");
    else       asm volatile("s_waitcnt vmcnt(0)" ::: "memory");
    __builtin_amdgcn_s_barrier();
    __builtin_amdgcn_sched_barrier(0);
    if (s < 7) loadA(s + 1, aN0, aN1);          // 2 vmem (BEFORE next stage: FIFO)
    if (s < 6) stageW(s + 2, (s + 2) % 3);      // 4 vmem; buffer freed by barrier
    const float* tb = &tiles[s % 3][(g * 8) * 128 + w * 32 + col];
    bf16x8 b0, b1;
#pragma unroll
    for (int j = 0; j < 8; ++j) {
      b0[j] = (short)f2bf(tb[j * 128]);
      b1[j] = (short)f2bf(tb[j * 128 + 16]);
    }
    acc00 = MFMA16(aC0, b0, acc00, 0, 0, 0);
    acc01 = MFMA16(aC0, b1, acc01, 0, 0, 0);
    acc10 = MFMA16(aC1, b0, acc10, 0, 0, 0);
    acc11 = MFMA16(aC1, b1, acc11, 0, 0, 0);
    aC0 = aN0; aC1 = aN1;
  }

  unsigned short* pp = pre_part + (size_t)h * 128 * CHUNK;
  const unsigned nc = n0 + w * 32 + col;
#pragma unroll
  for (int i = 0; i < 4; ++i) {
    unsigned row0 = r * RS + g * 4 + i;
    unsigned row1 = row0 + 16;
    pp[(size_t)row0 * CHUNK + nc]      = f2bf(acc00[i]);
    pp[(size_t)row0 * CHUNK + nc + 16] = f2bf(acc01[i]);
    pp[(size_t)row1 * CHUNK + nc]      = f2bf(acc10[i]);
    pp[(size_t)row1 * CHUNK + nc + 16] = f2bf(acc11[i]);
  }
}

// ---------------------------------------------------------------------------
// Kernel 3: lnpack. One block per output row (128 blocks x 256 thr).
// pre = sum of 8 bf16 partials + b_enc; block-reduce mean/var; LN + ReLU;
// pack featfrag[r][mt][kt(128)][lane][8] bf16 (decoder A-frag order).
// ---------------------------------------------------------------------------
__global__ __launch_bounds__(256) void lnpack_kernel(
    const unsigned short* __restrict__ pre_part, const float* __restrict__ benc,
    const float* __restrict__ gamma, const float* __restrict__ beta,
    unsigned short* __restrict__ featfrag) {
  const unsigned row = blockIdx.x;              // 0..127
  const unsigned r = row >> 5, m = row & 31u;
  const unsigned t = threadIdx.x;
  const unsigned c0 = t * 16;

  const float* bb = benc + (size_t)r * CHUNK + c0;
  float v[16];
#pragma unroll
  for (int j = 0; j < 16; ++j) v[j] = bb[j];
#pragma unroll
  for (int hh = 0; hh < 8; ++hh) {
    const unsigned short* ph = pre_part + ((size_t)hh * 128 + row) * CHUNK + c0;
    bf16x8 ua = *(const bf16x8*)ph, ub = *(const bf16x8*)(ph + 8);
#pragma unroll
    for (int j = 0; j < 8; ++j) {
      v[j]     += bf2f((unsigned short)ua[j]);
      v[j + 8] += bf2f((unsigned short)ub[j]);
    }
  }
  float s = 0.f, q = 0.f;
#pragma unroll
  for (int j = 0; j < 16; ++j) { s += v[j]; q += v[j] * v[j]; }
#pragma unroll
  for (int off = 1; off < 64; off <<= 1) {
    s += __shfl_xor(s, off, 64);
    q += __shfl_xor(q, off, 64);
  }
  __shared__ float ls[4], lq[4];
  if ((t & 63u) == 0) { ls[t >> 6] = s; lq[t >> 6] = q; }
  __syncthreads();
  s = ls[0] + ls[1] + ls[2] + ls[3];
  q = lq[0] + lq[1] + lq[2] + lq[3];
  float mu  = s * (1.f / CHUNK);
  float var = q * (1.f / CHUNK) - mu * mu;
  float rsd = rsqrtf(var + LN_EPS);

  const float* gp = gamma + (size_t)r * CHUNK + c0;
  const float* bp = beta  + (size_t)r * CHUNK + c0;
  const unsigned mt = m >> 4;
#pragma unroll
  for (int half = 0; half < 2; ++half) {
    bf16x8 o;
#pragma unroll
    for (int j = 0; j < 8; ++j) {
      float x = (v[half * 8 + j] - mu) * rsd * gp[half * 8 + j] + bp[half * 8 + j];
      o[j] = (short)f2bf(fmaxf(x, 0.f));
    }
    unsigned k = c0 + half * 8;
    unsigned kt = k >> 5, grp = (k >> 3) & 3u, ln = (m & 15u) + 16u * grp;
    *(bf16x8*)(featfrag + (((size_t)(r * 2 + mt) * 128 + kt) * 64 + ln) * 8) = o;
  }
}

// ---------------------------------------------------------------------------
// Kernel 4: decoder. grid = 4r x 16h x 16nt = 1024 blocks, 256 thr (4 waves).
// Block tile 32m x 128n over D_IN, K' = 256 (8 steps of 32). Same cooperative
// staging + counted-vmcnt barrier loop as enc. Writes bf16 partial h.
// ---------------------------------------------------------------------------
__global__ __launch_bounds__(256) void dec_kernel(
    const unsigned short* __restrict__ featfrag, const float* __restrict__ Wdec,
    unsigned short* __restrict__ part) {
  const unsigned r = blockIdx.x >> 8;
  const unsigned h = (blockIdx.x >> 4) & 15u;
  const unsigned nt = blockIdx.x & 15u;
  const unsigned n0 = nt * 128;
  const unsigned w = threadIdx.x >> 6, lane = threadIdx.x & 63u;
  const unsigned col = lane & 15u, g = lane >> 4;

  __shared__ float tiles[3][32 * 128];

  const unsigned srow = w * 8 + (lane >> 5);
  const unsigned scol = (lane & 31u) * 4u;
  const float* gbase = Wdec + ((size_t)(r * CHUNK + h * 256 + srow)) * D_IN + n0 + scol;
  const unsigned short* fa0 = featfrag + ((size_t)(r * 2 + 0) * 128) * 512 + (size_t)lane * 8;
  const unsigned short* fa1 = featfrag + ((size_t)(r * 2 + 1) * 128) * 512 + (size_t)lane * 8;

  f32x4 acc00 = {0.f,0.f,0.f,0.f}, acc01 = acc00, acc10 = acc00, acc11 = acc00;

  auto stageW = [&](int s, int b) {
#pragma unroll
    for (int l = 0; l < 4; ++l) {
      const float* gp = gbase + (size_t)(s * 32 + 2 * l) * D_IN;
      gload_lds16(gp, &tiles[b][(w * 8 + 2 * l) * 128]);
    }
  };
  auto loadA = [&](int s, bf16x8& A0, bf16x8& A1) {
    unsigned kt = h * 8 + (unsigned)s;
    A0 = *(const bf16x8*)(fa0 + (size_t)kt * 512);
    A1 = *(const bf16x8*)(fa1 + (size_t)kt * 512);
  };

  bf16x8 aC0, aC1, aN0, aN1;
  stageW(0, 0);
  loadA(0, aC0, aC1);
  stageW(1, 1);

#pragma unroll
  for (int s = 0; s < 8; ++s) {
    if (s < 7) asm volatile("s_waitcnt vmcnt(4)" ::: "memory");
    else       asm volatile("s_waitcnt vmcnt(0)" ::: "memory");
    __builtin_amdgcn_s_barrier();
    __builtin_amdgcn_sched_barrier(0);
    if (s < 7) loadA(s + 1, aN0, aN1);
    if (s < 6) stageW(s + 2, (s + 2) % 3);
    const float* tb = &tiles[s % 3][(g * 8) * 128 + w * 32 + col];
    bf16x8 b0, b1;
#pragma unroll
    for (int j = 0; j < 8; ++j) {
      b0[j] = (short)f2bf(tb[j * 128]);
      b1[j] = (short)f2bf(tb[j * 128 + 16]);
    }
    acc00 = MFMA16(aC0, b0, acc00, 0, 0, 0);
    acc01 = MFMA16(aC0, b1, acc01, 0, 0, 0);
    acc10 = MFMA16(aC1, b0, acc10, 0, 0, 0);
    acc11 = MFMA16(aC1, b1, acc11, 0, 0, 0);
    aC0 = aN0; aC1 = aN1;
  }

  unsigned short* pp = part + (size_t)h * 128 * D_IN;
  const unsigned nc = n0 + w * 32 + col;
#pragma unroll
  for (int i = 0; i < 4; ++i) {
    unsigned row0 = r * RS + g * 4 + i;
    unsigned row1 = row0 + 16;
    pp[(size_t)row0 * D_IN + nc]      = f2bf(acc00[i]);
    pp[(size_t)row0 * D_IN + nc + 16] = f2bf(acc01[i]);
    pp[(size_t)row1 * D_IN + nc]      = f2bf(acc10[i]);
    pp[(size_t)row1 * D_IN + nc + 16] = f2bf(acc11[i]);
  }
}

// ---------------------------------------------------------------------------
// Kernel 5: out = sum of 16 bf16 partials + b_dec (one float4 per thread).
// ---------------------------------------------------------------------------
__global__ __launch_bounds__(256) void finish_kernel(
    const unsigned short* __restrict__ part, const float* __restrict__ bdec,
    float* __restrict__ out) {
  unsigned i = blockIdx.x * 256u + threadIdx.x;           // f32x4 index, 65536
  f32x4 o = ((const f32x4*)bdec)[i & 511u];
#pragma unroll
  for (int hh = 0; hh < 16; ++hh) {
    bf16x4 u = *(const bf16x4*)(part + (size_t)hh * 128 * D_IN + (size_t)i * 4);
#pragma unroll
    for (int j = 0; j < 4; ++j) o[j] += bf2f((unsigned short)u[j]);
  }
  ((f32x4*)out)[i] = o;
}

// ---------------------------------------------------------------------------
extern "C" void kernel_launch(void* const* d_in, const int* in_sizes, int n_in,
                              void* d_out, int out_size, void* d_ws, size_t ws_size,
                              hipStream_t stream) {
  const float* acts = (const float*)d_in[0];
  const float* Wenc = (const float*)d_in[1];
  const float* benc = (const float*)d_in[2];
  const float* bdec = (const float*)d_in[3];
  const float* pos  = (const float*)d_in[4];
  const float* lnw  = (const float*)d_in[5];
  const float* lnb  = (const float*)d_in[6];
  const float* Wdec = (const float*)d_in[7];
  float* out = (float*)d_out;

  char* ws = (char*)d_ws;
  unsigned short* xfrag   = (unsigned short*)ws;                            // 512 KiB
  unsigned short* pre_prt = (unsigned short*)(ws + 512 * 1024);             // 8 MiB (8 bf16 partials)
  unsigned short* featfrg = (unsigned short*)(ws + 512 * 1024 + 8*1024*1024);   // 1 MiB
  unsigned short* part    = (unsigned short*)(ws + 512 * 1024 + 9*1024*1024);   // 8 MiB (16 bf16 partials)

  prep_kernel  <<<128,  256, 0, stream>>>(acts, pos, bdec, xfrag);
  enc_kernel   <<<1024, 256, 0, stream>>>(xfrag, Wenc, pre_prt);
  lnpack_kernel<<<128,  256, 0, stream>>>(pre_prt, benc, lnw, lnb, featfrg);
  dec_kernel   <<<1024, 256, 0, stream>>>(featfrg, Wdec, part);
  finish_kernel<<<256,  256, 0, stream>>>(part, bdec, out);
}

// Round 12
// 61.383 us; speedup vs baseline: 1.1333x; 1.1333x over previous
//
#include <hip/hip_runtime.h>
#include <hip/hip_bf16.h>
#include <stdint.h>

// PositionalSAE on MI355X — round 12.
// Round-9 GEMM engine (barrier-free private-slice staging, counted vmcnt(6))
// with split-K removed: enc writes bf16 pre directly (512 blk x 4 waves,
// 16 steps); dec does full K=4096 per block (256 blk x 8 waves, 16 steps of
// 256 k-rows) and writes d_out (+b_dec) directly. No part, no finish kernel.

#define D_IN   2048
#define CHUNK  4096
#define RS     32
#define LN_EPS 1e-5f

typedef __attribute__((ext_vector_type(8))) short bf16x8;
typedef __attribute__((ext_vector_type(4))) float f32x4;

#define AS1 __attribute__((address_space(1)))
#define AS3 __attribute__((address_space(3)))

__device__ __forceinline__ void gload_lds16(const float* g, float* l) {
  __builtin_amdgcn_global_load_lds((const AS1 unsigned int*)g,
                                   (AS3 unsigned int*)l, 16, 0, 0);
}

__device__ __forceinline__ unsigned short f2bf(float f) {
  unsigned int u = __float_as_uint(f);
  u += 0x7fffu + ((u >> 16) & 1u);
  return (unsigned short)(u >> 16);
}
__device__ __forceinline__ float bf2f(unsigned short s) {
  return __uint_as_float(((unsigned int)s) << 16);
}

#define MFMA16 __builtin_amdgcn_mfma_f32_16x16x32_bf16

// ---------------------------------------------------------------------------
// Kernel 1: prep. xfrag[r][mt][kt(64)][lane(64)][8] bf16, MFMA A-frag order:
//   element j = x[m = mt*16 + (lane&15)][k = kt*32 + (lane>>4)*8 + j]
// x = acts + pos_emb[r] - b_dec.
// ---------------------------------------------------------------------------
__global__ __launch_bounds__(256) void prep_kernel(
    const float* __restrict__ acts, const float* __restrict__ pos,
    const float* __restrict__ bdec, unsigned short* __restrict__ xfrag) {
  unsigned tid = blockIdx.x * 256u + threadIdx.x;
  unsigned lane = tid & 63u, kt = (tid >> 6) & 63u, mt = (tid >> 12) & 1u, r = tid >> 13;
  unsigned m  = mt * 16 + (lane & 15u);
  unsigned k0 = kt * 32 + (lane >> 4) * 8;
  const float* ap = acts + (size_t)(r * RS + m) * D_IN + k0;
  const float* pp = pos  + (size_t)r * D_IN + k0;
  const float* bp = bdec + k0;
  bf16x8 v;
#pragma unroll
  for (int j = 0; j < 8; ++j) v[j] = (short)f2bf(ap[j] + pp[j] - bp[j]);
  *reinterpret_cast<bf16x8*>(xfrag + (size_t)tid * 8) = v;
}

// ---------------------------------------------------------------------------
// Kernel 2: encoder, full block-K. grid = 4r x 128nt = 512 blocks, 256 thr
// (4 waves). Wave w owns k-rows [w*32,+32) of each 128-row step; 16 steps
// cover K=2048. Private double-buffered staging, no barrier in loop, counted
// vmcnt(6). End LDS reduce across the 4 k-split waves; writes bf16 pre.
// ---------------------------------------------------------------------------
__global__ __launch_bounds__(256) void enc_kernel(
    const unsigned short* __restrict__ xfrag, const float* __restrict__ Wenc,
    unsigned short* __restrict__ pre) {
  const unsigned r = blockIdx.x >> 7, nt = blockIdx.x & 127u;
  const unsigned n0 = nt * 32;
  const unsigned w = threadIdx.x >> 6, lane = threadIdx.x & 63u;
  const unsigned col = lane & 15u, g = lane >> 4;

  __shared__ float smem[8192];                  // 32 KiB: tiles now, red later
  float* mytile = smem + w * 2048;              // [buf][32 rows][32 cols]

  const unsigned srow = lane >> 3, scol = (lane & 7u) * 4u;
  const float* gbase = Wenc
      + ((size_t)(r * D_IN + w * 32 + srow)) * CHUNK + n0 + scol;
  const unsigned short* xa0 = xfrag + ((size_t)(r * 2 + 0) * 64) * 512 + (size_t)lane * 8;
  const unsigned short* xa1 = xfrag + ((size_t)(r * 2 + 1) * 64) * 512 + (size_t)lane * 8;

  f32x4 acc00 = {0.f,0.f,0.f,0.f}, acc01 = acc00, acc10 = acc00, acc11 = acc00;

  auto stageW = [&](unsigned s, unsigned b) {
#pragma unroll
    for (int l = 0; l < 4; ++l) {
      const float* gp = gbase + (size_t)(s * 128 + l * 8) * CHUNK;
      gload_lds16(gp, mytile + b * 1024 + l * 256);
    }
  };

  bf16x8 aC0, aC1, aN0, aN1;
  {
    unsigned kt = w;
    aC0 = *(const bf16x8*)(xa0 + (size_t)kt * 512);
    aC1 = *(const bf16x8*)(xa1 + (size_t)kt * 512);
  }
  stageW(0, 0);

  unsigned buf = 0;
#pragma unroll
  for (int s = 0; s < 16; ++s) {
    if (s < 15) {
      unsigned kt = (s + 1) * 4 + w;
      aN0 = *(const bf16x8*)(xa0 + (size_t)kt * 512);
      aN1 = *(const bf16x8*)(xa1 + (size_t)kt * 512);
      stageW(s + 1, buf ^ 1);
      asm volatile("s_waitcnt vmcnt(6)" ::: "memory");   // stage(s)+A(s) done
    } else {
      asm volatile("s_waitcnt vmcnt(0)" ::: "memory");
    }
    const float* tb = mytile + buf * 1024 + g * 8 * 32 + col;
    bf16x8 b0, b1;
#pragma unroll
    for (int j = 0; j < 8; ++j) {
      b0[j] = (short)f2bf(tb[j * 32]);
      b1[j] = (short)f2bf(tb[j * 32 + 16]);
    }
    acc00 = MFMA16(aC0, b0, acc00, 0, 0, 0);
    acc01 = MFMA16(aC0, b1, acc01, 0, 0, 0);
    acc10 = MFMA16(aC1, b0, acc10, 0, 0, 0);
    acc11 = MFMA16(aC1, b1, acc11, 0, 0, 0);
    aC0 = aN0; aC1 = aN1; buf ^= 1;
  }

  __syncthreads();                              // tiles dead; smem becomes red
  float* red = smem;                            // [3][4][64][4] = 12 KiB
  if (w > 0) {
#pragma unroll
    for (int i = 0; i < 4; ++i) {
      red[(((w - 1) * 4 + 0) * 64 + lane) * 4 + i] = acc00[i];
      red[(((w - 1) * 4 + 1) * 64 + lane) * 4 + i] = acc01[i];
      red[(((w - 1) * 4 + 2) * 64 + lane) * 4 + i] = acc10[i];
      red[(((w - 1) * 4 + 3) * 64 + lane) * 4 + i] = acc11[i];
    }
  }
  __syncthreads();
  if (w == 0) {
    for (int q = 0; q < 3; ++q)
#pragma unroll
      for (int i = 0; i < 4; ++i) {
        acc00[i] += red[((q * 4 + 0) * 64 + lane) * 4 + i];
        acc01[i] += red[((q * 4 + 1) * 64 + lane) * 4 + i];
        acc10[i] += red[((q * 4 + 2) * 64 + lane) * 4 + i];
        acc11[i] += red[((q * 4 + 3) * 64 + lane) * 4 + i];
      }
#pragma unroll
    for (int i = 0; i < 4; ++i) {
      unsigned row0 = r * RS + g * 4 + i;       // mt=0
      unsigned row1 = row0 + 16;                // mt=1
      pre[(size_t)row0 * CHUNK + n0 + col]      = f2bf(acc00[i]);
      pre[(size_t)row0 * CHUNK + n0 + 16 + col] = f2bf(acc01[i]);
      pre[(size_t)row1 * CHUNK + n0 + col]      = f2bf(acc10[i]);
      pre[(size_t)row1 * CHUNK + n0 + 16 + col] = f2bf(acc11[i]);
    }
  }
}

// ---------------------------------------------------------------------------
// Kernel 3: lnpack. One block per output row (128 blocks x 256 thr).
// v = pre(bf16) + b_enc; block-reduce mean/var; LN + ReLU; pack
// featfrag[r][mt][kt(128)][lane][8] bf16 (decoder A-frag order).
// ---------------------------------------------------------------------------
__global__ __launch_bounds__(256) void lnpack_kernel(
    const unsigned short* __restrict__ pre, const float* __restrict__ benc,
    const float* __restrict__ gamma, const float* __restrict__ beta,
    unsigned short* __restrict__ featfrag) {
  const unsigned row = blockIdx.x;              // 0..127
  const unsigned r = row >> 5, m = row & 31u;
  const unsigned t = threadIdx.x;
  const unsigned c0 = t * 16;

  const unsigned short* p0 = pre + (size_t)row * CHUNK + c0;
  const float* bb = benc + (size_t)r * CHUNK + c0;

  bf16x8 ua = *(const bf16x8*)p0, ub = *(const bf16x8*)(p0 + 8);

  float v[16];
  float s = 0.f, q = 0.f;
#pragma unroll
  for (int j = 0; j < 8; ++j) {
    v[j]     = bf2f((unsigned short)ua[j]) + bb[j];
    v[j + 8] = bf2f((unsigned short)ub[j]) + bb[j + 8];
  }
#pragma unroll
  for (int j = 0; j < 16; ++j) { s += v[j]; q += v[j] * v[j]; }
#pragma unroll
  for (int off = 1; off < 64; off <<= 1) {
    s += __shfl_xor(s, off, 64);
    q += __shfl_xor(q, off, 64);
  }
  __shared__ float ls[4], lq[4];
  if ((t & 63u) == 0) { ls[t >> 6] = s; lq[t >> 6] = q; }
  __syncthreads();
  s = ls[0] + ls[1] + ls[2] + ls[3];
  q = lq[0] + lq[1] + lq[2] + lq[3];
  float mu  = s * (1.f / CHUNK);
  float var = q * (1.f / CHUNK) - mu * mu;
  float rsd = rsqrtf(var + LN_EPS);

  const float* gp = gamma + (size_t)r * CHUNK + c0;
  const float* bp = beta  + (size_t)r * CHUNK + c0;
  const unsigned mt = m >> 4;
#pragma unroll
  for (int half = 0; half < 2; ++half) {
    bf16x8 o;
#pragma unroll
    for (int j = 0; j < 8; ++j) {
      float x = (v[half * 8 + j] - mu) * rsd * gp[half * 8 + j] + bp[half * 8 + j];
      o[j] = (short)f2bf(fmaxf(x, 0.f));
    }
    unsigned k = c0 + half * 8;
    unsigned kt = k >> 5, grp = (k >> 3) & 3u, ln = (m & 15u) + 16u * grp;
    *(bf16x8*)(featfrag + (((size_t)(r * 2 + mt) * 128 + kt) * 64 + ln) * 8) = o;
  }
}

// ---------------------------------------------------------------------------
// Kernel 4: decoder, full block-K. grid = 4r x 64nt = 256 blocks, 512 thr
// (8 waves). Wave w owns k-rows [w*32,+32) of each 256-row step; 16 steps
// cover K=4096. Same barrier-free private-slice pipeline (per-step issues:
// 2 A loads + 4 stage loads -> vmcnt(6) unchanged). End LDS reduce across
// the 8 k-split waves; writes d_out directly (+b_dec).
// ---------------------------------------------------------------------------
__global__ __launch_bounds__(512) void dec_kernel(
    const unsigned short* __restrict__ featfrag, const float* __restrict__ Wdec,
    const float* __restrict__ bdec, float* __restrict__ out) {
  const unsigned r = blockIdx.x >> 6, nt = blockIdx.x & 63u;
  const unsigned n0 = nt * 32;
  const unsigned w = threadIdx.x >> 6, lane = threadIdx.x & 63u;
  const unsigned col = lane & 15u, g = lane >> 4;

  __shared__ float smem[16384];                 // 64 KiB: tiles now, red later
  float* mytile = smem + w * 2048;

  const unsigned srow = lane >> 3, scol = (lane & 7u) * 4u;
  const float* gbase = Wdec
      + ((size_t)(r * CHUNK + w * 32 + srow)) * D_IN + n0 + scol;
  const unsigned short* fa0 = featfrag + ((size_t)(r * 2 + 0) * 128) * 512 + (size_t)lane * 8;
  const unsigned short* fa1 = featfrag + ((size_t)(r * 2 + 1) * 128) * 512 + (size_t)lane * 8;

  f32x4 acc00 = {0.f,0.f,0.f,0.f}, acc01 = acc00, acc10 = acc00, acc11 = acc00;

  auto stageW = [&](unsigned s, unsigned b) {
#pragma unroll
    for (int l = 0; l < 4; ++l) {
      const float* gp = gbase + (size_t)(s * 256 + l * 8) * D_IN;
      gload_lds16(gp, mytile + b * 1024 + l * 256);
    }
  };

  bf16x8 aC0, aC1, aN0, aN1;
  {
    unsigned kt = w;
    aC0 = *(const bf16x8*)(fa0 + (size_t)kt * 512);
    aC1 = *(const bf16x8*)(fa1 + (size_t)kt * 512);
  }
  stageW(0, 0);

  unsigned buf = 0;
#pragma unroll
  for (int s = 0; s < 16; ++s) {
    if (s < 15) {
      unsigned kt = (s + 1) * 8 + w;
      aN0 = *(const bf16x8*)(fa0 + (size_t)kt * 512);
      aN1 = *(const bf16x8*)(fa1 + (size_t)kt * 512);
      stageW(s + 1, buf ^ 1);
      asm volatile("s_waitcnt vmcnt(6)" ::: "memory");
    } else {
      asm volatile("s_waitcnt vmcnt(0)" ::: "memory");
    }
    const float* tb = mytile + buf * 1024 + g * 8 * 32 + col;
    bf16x8 b0, b1;
#pragma unroll
    for (int j = 0; j < 8; ++j) {
      b0[j] = (short)f2bf(tb[j * 32]);
      b1[j] = (short)f2bf(tb[j * 32 + 16]);
    }
    acc00 = MFMA16(aC0, b0, acc00, 0, 0, 0);
    acc01 = MFMA16(aC0, b1, acc01, 0, 0, 0);
    acc10 = MFMA16(aC1, b0, acc10, 0, 0, 0);
    acc11 = MFMA16(aC1, b1, acc11, 0, 0, 0);
    aC0 = aN0; aC1 = aN1; buf ^= 1;
  }

  __syncthreads();                              // tiles dead; smem becomes red
  float* red = smem;                            // [7][4][64][4] = 28 KiB
  if (w > 0) {
#pragma unroll
    for (int i = 0; i < 4; ++i) {
      red[(((w - 1) * 4 + 0) * 64 + lane) * 4 + i] = acc00[i];
      red[(((w - 1) * 4 + 1) * 64 + lane) * 4 + i] = acc01[i];
      red[(((w - 1) * 4 + 2) * 64 + lane) * 4 + i] = acc10[i];
      red[(((w - 1) * 4 + 3) * 64 + lane) * 4 + i] = acc11[i];
    }
  }
  __syncthreads();
  if (w == 0) {
    for (int q = 0; q < 7; ++q)
#pragma unroll
      for (int i = 0; i < 4; ++i) {
        acc00[i] += red[((q * 4 + 0) * 64 + lane) * 4 + i];
        acc01[i] += red[((q * 4 + 1) * 64 + lane) * 4 + i];
        acc10[i] += red[((q * 4 + 2) * 64 + lane) * 4 + i];
        acc11[i] += red[((q * 4 + 3) * 64 + lane) * 4 + i];
      }
    float b0 = bdec[n0 + col], b1 = bdec[n0 + 16 + col];
#pragma unroll
    for (int i = 0; i < 4; ++i) {
      unsigned row0 = r * RS + g * 4 + i;
      unsigned row1 = row0 + 16;
      out[(size_t)row0 * D_IN + n0 + col]      = acc00[i] + b0;
      out[(size_t)row0 * D_IN + n0 + 16 + col] = acc01[i] + b1;
      out[(size_t)row1 * D_IN + n0 + col]      = acc10[i] + b0;
      out[(size_t)row1 * D_IN + n0 + 16 + col] = acc11[i] + b1;
    }
  }
}

// ---------------------------------------------------------------------------
extern "C" void kernel_launch(void* const* d_in, const int* in_sizes, int n_in,
                              void* d_out, int out_size, void* d_ws, size_t ws_size,
                              hipStream_t stream) {
  const float* acts = (const float*)d_in[0];
  const float* Wenc = (const float*)d_in[1];
  const float* benc = (const float*)d_in[2];
  const float* bdec = (const float*)d_in[3];
  const float* pos  = (const float*)d_in[4];
  const float* lnw  = (const float*)d_in[5];
  const float* lnb  = (const float*)d_in[6];
  const float* Wdec = (const float*)d_in[7];
  float* out = (float*)d_out;

  char* ws = (char*)d_ws;
  unsigned short* xfrag   = (unsigned short*)ws;                          // 512 KiB
  unsigned short* pre     = (unsigned short*)(ws + 512 * 1024);           // 1 MiB (bf16)
  unsigned short* featfrg = (unsigned short*)(ws + 1536 * 1024);          // 1 MiB

  prep_kernel  <<<128, 256, 0, stream>>>(acts, pos, bdec, xfrag);
  enc_kernel   <<<512, 256, 0, stream>>>(xfrag, Wenc, pre);
  lnpack_kernel<<<128, 256, 0, stream>>>(pre, benc, lnw, lnb, featfrg);
  dec_kernel   <<<256, 512, 0, stream>>>(featfrg, Wdec, bdec, out);
}

// Round 13
// 60.644 us; speedup vs baseline: 1.1471x; 1.0122x over previous
//
#include <hip/hip_runtime.h>
#include <hip/hip_bf16.h>
#include <stdint.h>

// PositionalSAE on MI355X — round 13.
// R12 + enc converted to BN=64 (256-B contiguous staging spans) as a clean
// granularity A/B. enc: 256 blocks x 4 waves, per-wave private 32k x 64n
// slice, barrier-free, counted vmcnt(10). dec/prep/lnpack identical to R12.

#define D_IN   2048
#define CHUNK  4096
#define RS     32
#define LN_EPS 1e-5f

typedef __attribute__((ext_vector_type(8))) short bf16x8;
typedef __attribute__((ext_vector_type(4))) float f32x4;

#define AS1 __attribute__((address_space(1)))
#define AS3 __attribute__((address_space(3)))

__device__ __forceinline__ void gload_lds16(const float* g, float* l) {
  __builtin_amdgcn_global_load_lds((const AS1 unsigned int*)g,
                                   (AS3 unsigned int*)l, 16, 0, 0);
}

__device__ __forceinline__ unsigned short f2bf(float f) {
  unsigned int u = __float_as_uint(f);
  u += 0x7fffu + ((u >> 16) & 1u);
  return (unsigned short)(u >> 16);
}
__device__ __forceinline__ float bf2f(unsigned short s) {
  return __uint_as_float(((unsigned int)s) << 16);
}

#define MFMA16 __builtin_amdgcn_mfma_f32_16x16x32_bf16

// ---------------------------------------------------------------------------
// Kernel 1: prep. xfrag[r][mt][kt(64)][lane(64)][8] bf16, MFMA A-frag order:
//   element j = x[m = mt*16 + (lane&15)][k = kt*32 + (lane>>4)*8 + j]
// x = acts + pos_emb[r] - b_dec.
// ---------------------------------------------------------------------------
__global__ __launch_bounds__(256) void prep_kernel(
    const float* __restrict__ acts, const float* __restrict__ pos,
    const float* __restrict__ bdec, unsigned short* __restrict__ xfrag) {
  unsigned tid = blockIdx.x * 256u + threadIdx.x;
  unsigned lane = tid & 63u, kt = (tid >> 6) & 63u, mt = (tid >> 12) & 1u, r = tid >> 13;
  unsigned m  = mt * 16 + (lane & 15u);
  unsigned k0 = kt * 32 + (lane >> 4) * 8;
  const float* ap = acts + (size_t)(r * RS + m) * D_IN + k0;
  const float* pp = pos  + (size_t)r * D_IN + k0;
  const float* bp = bdec + k0;
  bf16x8 v;
#pragma unroll
  for (int j = 0; j < 8; ++j) v[j] = (short)f2bf(ap[j] + pp[j] - bp[j]);
  *reinterpret_cast<bf16x8*>(xfrag + (size_t)tid * 8) = v;
}

// ---------------------------------------------------------------------------
// Kernel 2: encoder, BN=64 full block-K. grid = 4r x 64nt = 256 blocks,
// 256 thr (4 waves). Wave w owns k-rows [w*32,+32) of each 128-row step;
// 16 steps cover K=2048. Private slice 32k x 64n (8 KB/buffer, 2 buffers);
// staging spans 256 B contiguous (gload = 4 rows x 256 B). Barrier-free,
// counted vmcnt(10). End LDS reduce over 4 k-split waves; writes bf16 pre.
// ---------------------------------------------------------------------------
__global__ __launch_bounds__(256) void enc_kernel(
    const unsigned short* __restrict__ xfrag, const float* __restrict__ Wenc,
    unsigned short* __restrict__ pre) {
  const unsigned r = blockIdx.x >> 6, nt = blockIdx.x & 63u;
  const unsigned n0 = nt * 64;
  const unsigned w = threadIdx.x >> 6, lane = threadIdx.x & 63u;
  const unsigned col = lane & 15u, g = lane >> 4;

  __shared__ float smem[16384];                 // 64 KiB: tiles now, red later
  float* mytile = smem + w * 4096;              // [buf(2)][32 rows][64 cols]

  const unsigned srow = lane >> 4;              // 0..3
  const unsigned scol = (lane & 15u) * 4u;      // 0..60 floats (256B rows)
  const float* gbase = Wenc
      + ((size_t)(r * D_IN + w * 32 + srow)) * CHUNK + n0 + scol;
  const unsigned short* xa0 = xfrag + ((size_t)(r * 2 + 0) * 64) * 512 + (size_t)lane * 8;
  const unsigned short* xa1 = xfrag + ((size_t)(r * 2 + 1) * 64) * 512 + (size_t)lane * 8;

  f32x4 acc0[4], acc1[4];
#pragma unroll
  for (int n = 0; n < 4; ++n) { acc0[n] = {0.f,0.f,0.f,0.f}; acc1[n] = acc0[n]; }

  auto stageW = [&](unsigned s, unsigned b) {
#pragma unroll
    for (int l = 0; l < 8; ++l) {               // 8 gloads x (4 rows x 256B)
      const float* gp = gbase + (size_t)(s * 128 + l * 4) * CHUNK;
      gload_lds16(gp, mytile + b * 2048 + l * 256);
    }
  };

  bf16x8 aC0, aC1, aN0, aN1;
  {
    unsigned kt = w;
    aC0 = *(const bf16x8*)(xa0 + (size_t)kt * 512);
    aC1 = *(const bf16x8*)(xa1 + (size_t)kt * 512);
  }
  stageW(0, 0);

  unsigned buf = 0;
#pragma unroll
  for (int s = 0; s < 16; ++s) {
    if (s < 15) {
      unsigned kt = (s + 1) * 4 + w;
      aN0 = *(const bf16x8*)(xa0 + (size_t)kt * 512);   // 2 vmem
      aN1 = *(const bf16x8*)(xa1 + (size_t)kt * 512);
      stageW(s + 1, buf ^ 1);                           // 8 vmem
      asm volatile("s_waitcnt vmcnt(10)" ::: "memory"); // stage(s)+A(s) done
    } else {
      asm volatile("s_waitcnt vmcnt(0)" ::: "memory");
    }
    const float* tb = mytile + buf * 2048 + g * 8 * 64 + col;
#pragma unroll
    for (int n = 0; n < 4; ++n) {
      bf16x8 bf;
#pragma unroll
      for (int j = 0; j < 8; ++j) bf[j] = (short)f2bf(tb[j * 64 + n * 16]);
      acc0[n] = MFMA16(aC0, bf, acc0[n], 0, 0, 0);
      acc1[n] = MFMA16(aC1, bf, acc1[n], 0, 0, 0);
    }
    aC0 = aN0; aC1 = aN1; buf ^= 1;
  }

  __syncthreads();                              // tiles dead; smem becomes red
  float* red = smem;                            // [3][8][64][4] = 24 KiB
  if (w > 0) {
#pragma unroll
    for (int n = 0; n < 4; ++n)
#pragma unroll
      for (int i = 0; i < 4; ++i) {
        red[(((w - 1) * 8 + n) * 64 + lane) * 4 + i]     = acc0[n][i];
        red[(((w - 1) * 8 + 4 + n) * 64 + lane) * 4 + i] = acc1[n][i];
      }
  }
  __syncthreads();
  if (w == 0) {
    for (int q = 0; q < 3; ++q)
#pragma unroll
      for (int n = 0; n < 4; ++n)
#pragma unroll
        for (int i = 0; i < 4; ++i) {
          acc0[n][i] += red[((q * 8 + n) * 64 + lane) * 4 + i];
          acc1[n][i] += red[((q * 8 + 4 + n) * 64 + lane) * 4 + i];
        }
#pragma unroll
    for (int n = 0; n < 4; ++n)
#pragma unroll
      for (int i = 0; i < 4; ++i) {
        unsigned row0 = r * RS + g * 4 + i;     // mt=0
        unsigned row1 = row0 + 16;              // mt=1
        pre[(size_t)row0 * CHUNK + n0 + n * 16 + col] = f2bf(acc0[n][i]);
        pre[(size_t)row1 * CHUNK + n0 + n * 16 + col] = f2bf(acc1[n][i]);
      }
  }
}

// ---------------------------------------------------------------------------
// Kernel 3: lnpack. One block per output row (128 blocks x 256 thr).
// v = pre(bf16) + b_enc; block-reduce mean/var; LN + ReLU; pack
// featfrag[r][mt][kt(128)][lane][8] bf16 (decoder A-frag order).
// ---------------------------------------------------------------------------
__global__ __launch_bounds__(256) void lnpack_kernel(
    const unsigned short* __restrict__ pre, const float* __restrict__ benc,
    const float* __restrict__ gamma, const float* __restrict__ beta,
    unsigned short* __restrict__ featfrag) {
  const unsigned row = blockIdx.x;              // 0..127
  const unsigned r = row >> 5, m = row & 31u;
  const unsigned t = threadIdx.x;
  const unsigned c0 = t * 16;

  const unsigned short* p0 = pre + (size_t)row * CHUNK + c0;
  const float* bb = benc + (size_t)r * CHUNK + c0;

  bf16x8 ua = *(const bf16x8*)p0, ub = *(const bf16x8*)(p0 + 8);

  float v[16];
  float s = 0.f, q = 0.f;
#pragma unroll
  for (int j = 0; j < 8; ++j) {
    v[j]     = bf2f((unsigned short)ua[j]) + bb[j];
    v[j + 8] = bf2f((unsigned short)ub[j]) + bb[j + 8];
  }
#pragma unroll
  for (int j = 0; j < 16; ++j) { s += v[j]; q += v[j] * v[j]; }
#pragma unroll
  for (int off = 1; off < 64; off <<= 1) {
    s += __shfl_xor(s, off, 64);
    q += __shfl_xor(q, off, 64);
  }
  __shared__ float ls[4], lq[4];
  if ((t & 63u) == 0) { ls[t >> 6] = s; lq[t >> 6] = q; }
  __syncthreads();
  s = ls[0] + ls[1] + ls[2] + ls[3];
  q = lq[0] + lq[1] + lq[2] + lq[3];
  float mu  = s * (1.f / CHUNK);
  float var = q * (1.f / CHUNK) - mu * mu;
  float rsd = rsqrtf(var + LN_EPS);

  const float* gp = gamma + (size_t)r * CHUNK + c0;
  const float* bp = beta  + (size_t)r * CHUNK + c0;
  const unsigned mt = m >> 4;
#pragma unroll
  for (int half = 0; half < 2; ++half) {
    bf16x8 o;
#pragma unroll
    for (int j = 0; j < 8; ++j) {
      float x = (v[half * 8 + j] - mu) * rsd * gp[half * 8 + j] + bp[half * 8 + j];
      o[j] = (short)f2bf(fmaxf(x, 0.f));
    }
    unsigned k = c0 + half * 8;
    unsigned kt = k >> 5, grp = (k >> 3) & 3u, ln = (m & 15u) + 16u * grp;
    *(bf16x8*)(featfrag + (((size_t)(r * 2 + mt) * 128 + kt) * 64 + ln) * 8) = o;
  }
}

// ---------------------------------------------------------------------------
// Kernel 4: decoder, full block-K (identical to R12). grid = 4r x 64nt =
// 256 blocks, 512 thr (8 waves). Wave w owns k-rows [w*32,+32) of each
// 256-row step; 16 steps cover K=4096. Barrier-free, counted vmcnt(6).
// End LDS reduce over 8 waves; writes d_out (+b_dec).
// ---------------------------------------------------------------------------
__global__ __launch_bounds__(512) void dec_kernel(
    const unsigned short* __restrict__ featfrag, const float* __restrict__ Wdec,
    const float* __restrict__ bdec, float* __restrict__ out) {
  const unsigned r = blockIdx.x >> 6, nt = blockIdx.x & 63u;
  const unsigned n0 = nt * 32;
  const unsigned w = threadIdx.x >> 6, lane = threadIdx.x & 63u;
  const unsigned col = lane & 15u, g = lane >> 4;

  __shared__ float smem[16384];                 // 64 KiB: tiles now, red later
  float* mytile = smem + w * 2048;

  const unsigned srow = lane >> 3, scol = (lane & 7u) * 4u;
  const float* gbase = Wdec
      + ((size_t)(r * CHUNK + w * 32 + srow)) * D_IN + n0 + scol;
  const unsigned short* fa0 = featfrag + ((size_t)(r * 2 + 0) * 128) * 512 + (size_t)lane * 8;
  const unsigned short* fa1 = featfrag + ((size_t)(r * 2 + 1) * 128) * 512 + (size_t)lane * 8;

  f32x4 acc00 = {0.f,0.f,0.f,0.f}, acc01 = acc00, acc10 = acc00, acc11 = acc00;

  auto stageW = [&](unsigned s, unsigned b) {
#pragma unroll
    for (int l = 0; l < 4; ++l) {
      const float* gp = gbase + (size_t)(s * 256 + l * 8) * D_IN;
      gload_lds16(gp, mytile + b * 1024 + l * 256);
    }
  };

  bf16x8 aC0, aC1, aN0, aN1;
  {
    unsigned kt = w;
    aC0 = *(const bf16x8*)(fa0 + (size_t)kt * 512);
    aC1 = *(const bf16x8*)(fa1 + (size_t)kt * 512);
  }
  stageW(0, 0);

  unsigned buf = 0;
#pragma unroll
  for (int s = 0; s < 16; ++s) {
    if (s < 15) {
      unsigned kt = (s + 1) * 8 + w;
      aN0 = *(const bf16x8*)(fa0 + (size_t)kt * 512);
      aN1 = *(const bf16x8*)(fa1 + (size_t)kt * 512);
      stageW(s + 1, buf ^ 1);
      asm volatile("s_waitcnt vmcnt(6)" ::: "memory");
    } else {
      asm volatile("s_waitcnt vmcnt(0)" ::: "memory");
    }
    const float* tb = mytile + buf * 1024 + g * 8 * 32 + col;
    bf16x8 b0, b1;
#pragma unroll
    for (int j = 0; j < 8; ++j) {
      b0[j] = (short)f2bf(tb[j * 32]);
      b1[j] = (short)f2bf(tb[j * 32 + 16]);
    }
    acc00 = MFMA16(aC0, b0, acc00, 0, 0, 0);
    acc01 = MFMA16(aC0, b1, acc01, 0, 0, 0);
    acc10 = MFMA16(aC1, b0, acc10, 0, 0, 0);
    acc11 = MFMA16(aC1, b1, acc11, 0, 0, 0);
    aC0 = aN0; aC1 = aN1; buf ^= 1;
  }

  __syncthreads();                              // tiles dead; smem becomes red
  float* red = smem;                            // [7][4][64][4] = 28 KiB
  if (w > 0) {
#pragma unroll
    for (int i = 0; i < 4; ++i) {
      red[(((w - 1) * 4 + 0) * 64 + lane) * 4 + i] = acc00[i];
      red[(((w - 1) * 4 + 1) * 64 + lane) * 4 + i] = acc01[i];
      red[(((w - 1) * 4 + 2) * 64 + lane) * 4 + i] = acc10[i];
      red[(((w - 1) * 4 + 3) * 64 + lane) * 4 + i] = acc11[i];
    }
  }
  __syncthreads();
  if (w == 0) {
    for (int q = 0; q < 7; ++q)
#pragma unroll
      for (int i = 0; i < 4; ++i) {
        acc00[i] += red[((q * 4 + 0) * 64 + lane) * 4 + i];
        acc01[i] += red[((q * 4 + 1) * 64 + lane) * 4 + i];
        acc10[i] += red[((q * 4 + 2) * 64 + lane) * 4 + i];
        acc11[i] += red[((q * 4 + 3) * 64 + lane) * 4 + i];
      }
    float b0 = bdec[n0 + col], b1 = bdec[n0 + 16 + col];
#pragma unroll
    for (int i = 0; i < 4; ++i) {
      unsigned row0 = r * RS + g * 4 + i;
      unsigned row1 = row0 + 16;
      out[(size_t)row0 * D_IN + n0 + col]      = acc00[i] + b0;
      out[(size_t)row0 * D_IN + n0 + 16 + col] = acc01[i] + b1;
      out[(size_t)row1 * D_IN + n0 + col]      = acc10[i] + b0;
      out[(size_t)row1 * D_IN + n0 + 16 + col] = acc11[i] + b1;
    }
  }
}

// ---------------------------------------------------------------------------
extern "C" void kernel_launch(void* const* d_in, const int* in_sizes, int n_in,
                              void* d_out, int out_size, void* d_ws, size_t ws_size,
                              hipStream_t stream) {
  const float* acts = (const float*)d_in[0];
  const float* Wenc = (const float*)d_in[1];
  const float* benc = (const float*)d_in[2];
  const float* bdec = (const float*)d_in[3];
  const float* pos  = (const float*)d_in[4];
  const float* lnw  = (const float*)d_in[5];
  const float* lnb  = (const float*)d_in[6];
  const float* Wdec = (const float*)d_in[7];
  float* out = (float*)d_out;

  char* ws = (char*)d_ws;
  unsigned short* xfrag   = (unsigned short*)ws;                          // 512 KiB
  unsigned short* pre     = (unsigned short*)(ws + 512 * 1024);           // 1 MiB (bf16)
  unsigned short* featfrg = (unsigned short*)(ws + 1536 * 1024);          // 1 MiB

  prep_kernel  <<<128, 256, 0, stream>>>(acts, pos, bdec, xfrag);
  enc_kernel   <<<256, 256, 0, stream>>>(xfrag, Wenc, pre);
  lnpack_kernel<<<128, 256, 0, stream>>>(pre, benc, lnw, lnb, featfrg);
  dec_kernel   <<<256, 512, 0, stream>>>(featfrg, Wdec, bdec, out);
}

// Round 14
// 60.385 us; speedup vs baseline: 1.1520x; 1.0043x over previous
//
#include <hip/hip_runtime.h>
#include <hip/hip_bf16.h>
#include <stdint.h>

// PositionalSAE on MI355X — round 14.
// R13 + 3-deep staging ring (2-step-ahead prefetch) in both GEMMs to deepen
// HBM queues. Same barrier-free private-slice engine, FIFO-exact counted
// vmcnt: enc steady vmcnt(20), dec vmcnt(12). Everything else identical.

#define D_IN   2048
#define CHUNK  4096
#define RS     32
#define LN_EPS 1e-5f

typedef __attribute__((ext_vector_type(8))) short bf16x8;
typedef __attribute__((ext_vector_type(4))) float f32x4;

#define AS1 __attribute__((address_space(1)))
#define AS3 __attribute__((address_space(3)))

__device__ __forceinline__ void gload_lds16(const float* g, float* l) {
  __builtin_amdgcn_global_load_lds((const AS1 unsigned int*)g,
                                   (AS3 unsigned int*)l, 16, 0, 0);
}

__device__ __forceinline__ unsigned short f2bf(float f) {
  unsigned int u = __float_as_uint(f);
  u += 0x7fffu + ((u >> 16) & 1u);
  return (unsigned short)(u >> 16);
}
__device__ __forceinline__ float bf2f(unsigned short s) {
  return __uint_as_float(((unsigned int)s) << 16);
}

#define MFMA16 __builtin_amdgcn_mfma_f32_16x16x32_bf16

// ---------------------------------------------------------------------------
// Kernel 1: prep. xfrag[r][mt][kt(64)][lane(64)][8] bf16, MFMA A-frag order:
//   element j = x[m = mt*16 + (lane&15)][k = kt*32 + (lane>>4)*8 + j]
// x = acts + pos_emb[r] - b_dec.
// ---------------------------------------------------------------------------
__global__ __launch_bounds__(256) void prep_kernel(
    const float* __restrict__ acts, const float* __restrict__ pos,
    const float* __restrict__ bdec, unsigned short* __restrict__ xfrag) {
  unsigned tid = blockIdx.x * 256u + threadIdx.x;
  unsigned lane = tid & 63u, kt = (tid >> 6) & 63u, mt = (tid >> 12) & 1u, r = tid >> 13;
  unsigned m  = mt * 16 + (lane & 15u);
  unsigned k0 = kt * 32 + (lane >> 4) * 8;
  const float* ap = acts + (size_t)(r * RS + m) * D_IN + k0;
  const float* pp = pos  + (size_t)r * D_IN + k0;
  const float* bp = bdec + k0;
  bf16x8 v;
#pragma unroll
  for (int j = 0; j < 8; ++j) v[j] = (short)f2bf(ap[j] + pp[j] - bp[j]);
  *reinterpret_cast<bf16x8*>(xfrag + (size_t)tid * 8) = v;
}

// ---------------------------------------------------------------------------
// Kernel 2: encoder, BN=64, 3-deep ring. grid = 4r x 64nt = 256 blocks,
// 256 thr (4 waves). Wave w owns k-rows [w*32,+32) of each 128-row step;
// 16 steps cover K=2048. Private slice 32k x 64n (8 KB x 3 buffers);
// 256-B staging spans. Barrier-free; steady vmcnt(20) (2 steps queued).
// End LDS reduce over 4 k-split waves; writes bf16 pre.
// ---------------------------------------------------------------------------
__global__ __launch_bounds__(256) void enc_kernel(
    const unsigned short* __restrict__ xfrag, const float* __restrict__ Wenc,
    unsigned short* __restrict__ pre) {
  const unsigned r = blockIdx.x >> 6, nt = blockIdx.x & 63u;
  const unsigned n0 = nt * 64;
  const unsigned w = threadIdx.x >> 6, lane = threadIdx.x & 63u;
  const unsigned col = lane & 15u, g = lane >> 4;

  __shared__ float smem[24576];                 // 96 KiB: tiles now, red later
  float* mytile = smem + w * 6144;              // [buf(3)][32 rows][64 cols]

  const unsigned srow = lane >> 4;              // 0..3
  const unsigned scol = (lane & 15u) * 4u;      // 256B rows
  const float* gbase = Wenc
      + ((size_t)(r * D_IN + w * 32 + srow)) * CHUNK + n0 + scol;
  const unsigned short* xa0 = xfrag + ((size_t)(r * 2 + 0) * 64) * 512 + (size_t)lane * 8;
  const unsigned short* xa1 = xfrag + ((size_t)(r * 2 + 1) * 64) * 512 + (size_t)lane * 8;

  f32x4 acc0[4], acc1[4];
#pragma unroll
  for (int n = 0; n < 4; ++n) { acc0[n] = {0.f,0.f,0.f,0.f}; acc1[n] = acc0[n]; }

  auto stageW = [&](unsigned s, unsigned b) {
#pragma unroll
    for (int l = 0; l < 8; ++l) {               // 8 gloads x (4 rows x 256 B)
      const float* gp = gbase + (size_t)(s * 128 + l * 4) * CHUNK;
      gload_lds16(gp, mytile + b * 2048 + l * 256);
    }
  };
  auto loadA = [&](unsigned s, bf16x8& A0, bf16x8& A1) {
    unsigned kt = s * 4 + w;
    A0 = *(const bf16x8*)(xa0 + (size_t)kt * 512);
    A1 = *(const bf16x8*)(xa1 + (size_t)kt * 512);
  };

  // prologue: A(0), stage(0), A(1), stage(1)  (per-step issue order: A, stage)
  bf16x8 aC0, aC1, aN0, aN1, aF0, aF1;
  loadA(0, aC0, aC1);
  stageW(0, 0);
  loadA(1, aN0, aN1);
  stageW(1, 1);

  unsigned buf = 0;
#pragma unroll
  for (int s = 0; s < 16; ++s) {
    if (s < 14) {
      loadA(s + 2, aF0, aF1);                   // 2 vmem
      stageW(s + 2, (s + 2) % 3);               // 8 vmem
      asm volatile("s_waitcnt vmcnt(20)" ::: "memory"); // retire A(s)+stage(s)
    } else if (s == 14) {
      asm volatile("s_waitcnt vmcnt(10)" ::: "memory"); // retire through stage(14)
    } else {
      asm volatile("s_waitcnt vmcnt(0)" ::: "memory");
    }
    const float* tb = mytile + buf * 2048 + g * 8 * 64 + col;
#pragma unroll
    for (int n = 0; n < 4; ++n) {
      bf16x8 bf;
#pragma unroll
      for (int j = 0; j < 8; ++j) bf[j] = (short)f2bf(tb[j * 64 + n * 16]);
      acc0[n] = MFMA16(aC0, bf, acc0[n], 0, 0, 0);
      acc1[n] = MFMA16(aC1, bf, acc1[n], 0, 0, 0);
    }
    aC0 = aN0; aC1 = aN1; aN0 = aF0; aN1 = aF1;
    buf = (buf + 1) % 3;
  }

  __syncthreads();                              // tiles dead; smem becomes red
  float* red = smem;                            // [3][8][64][4] = 24 KiB
  if (w > 0) {
#pragma unroll
    for (int n = 0; n < 4; ++n)
#pragma unroll
      for (int i = 0; i < 4; ++i) {
        red[(((w - 1) * 8 + n) * 64 + lane) * 4 + i]     = acc0[n][i];
        red[(((w - 1) * 8 + 4 + n) * 64 + lane) * 4 + i] = acc1[n][i];
      }
  }
  __syncthreads();
  if (w == 0) {
    for (int q = 0; q < 3; ++q)
#pragma unroll
      for (int n = 0; n < 4; ++n)
#pragma unroll
        for (int i = 0; i < 4; ++i) {
          acc0[n][i] += red[((q * 8 + n) * 64 + lane) * 4 + i];
          acc1[n][i] += red[((q * 8 + 4 + n) * 64 + lane) * 4 + i];
        }
#pragma unroll
    for (int n = 0; n < 4; ++n)
#pragma unroll
      for (int i = 0; i < 4; ++i) {
        unsigned row0 = r * RS + g * 4 + i;     // mt=0
        unsigned row1 = row0 + 16;              // mt=1
        pre[(size_t)row0 * CHUNK + n0 + n * 16 + col] = f2bf(acc0[n][i]);
        pre[(size_t)row1 * CHUNK + n0 + n * 16 + col] = f2bf(acc1[n][i]);
      }
  }
}

// ---------------------------------------------------------------------------
// Kernel 3: lnpack. One block per output row (128 blocks x 256 thr).
// v = pre(bf16) + b_enc; block-reduce mean/var; LN + ReLU; pack
// featfrag[r][mt][kt(128)][lane][8] bf16 (decoder A-frag order).
// ---------------------------------------------------------------------------
__global__ __launch_bounds__(256) void lnpack_kernel(
    const unsigned short* __restrict__ pre, const float* __restrict__ benc,
    const float* __restrict__ gamma, const float* __restrict__ beta,
    unsigned short* __restrict__ featfrag) {
  const unsigned row = blockIdx.x;              // 0..127
  const unsigned r = row >> 5, m = row & 31u;
  const unsigned t = threadIdx.x;
  const unsigned c0 = t * 16;

  const unsigned short* p0 = pre + (size_t)row * CHUNK + c0;
  const float* bb = benc + (size_t)r * CHUNK + c0;

  bf16x8 ua = *(const bf16x8*)p0, ub = *(const bf16x8*)(p0 + 8);

  float v[16];
  float s = 0.f, q = 0.f;
#pragma unroll
  for (int j = 0; j < 8; ++j) {
    v[j]     = bf2f((unsigned short)ua[j]) + bb[j];
    v[j + 8] = bf2f((unsigned short)ub[j]) + bb[j + 8];
  }
#pragma unroll
  for (int j = 0; j < 16; ++j) { s += v[j]; q += v[j] * v[j]; }
#pragma unroll
  for (int off = 1; off < 64; off <<= 1) {
    s += __shfl_xor(s, off, 64);
    q += __shfl_xor(q, off, 64);
  }
  __shared__ float ls[4], lq[4];
  if ((t & 63u) == 0) { ls[t >> 6] = s; lq[t >> 6] = q; }
  __syncthreads();
  s = ls[0] + ls[1] + ls[2] + ls[3];
  q = lq[0] + lq[1] + lq[2] + lq[3];
  float mu  = s * (1.f / CHUNK);
  float var = q * (1.f / CHUNK) - mu * mu;
  float rsd = rsqrtf(var + LN_EPS);

  const float* gp = gamma + (size_t)r * CHUNK + c0;
  const float* bp = beta  + (size_t)r * CHUNK + c0;
  const unsigned mt = m >> 4;
#pragma unroll
  for (int half = 0; half < 2; ++half) {
    bf16x8 o;
#pragma unroll
    for (int j = 0; j < 8; ++j) {
      float x = (v[half * 8 + j] - mu) * rsd * gp[half * 8 + j] + bp[half * 8 + j];
      o[j] = (short)f2bf(fmaxf(x, 0.f));
    }
    unsigned k = c0 + half * 8;
    unsigned kt = k >> 5, grp = (k >> 3) & 3u, ln = (m & 15u) + 16u * grp;
    *(bf16x8*)(featfrag + (((size_t)(r * 2 + mt) * 128 + kt) * 64 + ln) * 8) = o;
  }
}

// ---------------------------------------------------------------------------
// Kernel 4: decoder, 3-deep ring. grid = 4r x 64nt = 256 blocks, 512 thr
// (8 waves). Wave w owns k-rows [w*32,+32) of each 256-row step; 16 steps
// cover K=4096. Private slice 32k x 32n (4 KB x 3 buffers); barrier-free;
// steady vmcnt(12). End LDS reduce over 8 waves; writes d_out (+b_dec).
// ---------------------------------------------------------------------------
__global__ __launch_bounds__(512) void dec_kernel(
    const unsigned short* __restrict__ featfrag, const float* __restrict__ Wdec,
    const float* __restrict__ bdec, float* __restrict__ out) {
  const unsigned r = blockIdx.x >> 6, nt = blockIdx.x & 63u;
  const unsigned n0 = nt * 32;
  const unsigned w = threadIdx.x >> 6, lane = threadIdx.x & 63u;
  const unsigned col = lane & 15u, g = lane >> 4;

  __shared__ float smem[24576];                 // 96 KiB: tiles now, red later
  float* mytile = smem + w * 3072;              // [buf(3)][32 rows][32 cols]

  const unsigned srow = lane >> 3, scol = (lane & 7u) * 4u;
  const float* gbase = Wdec
      + ((size_t)(r * CHUNK + w * 32 + srow)) * D_IN + n0 + scol;
  const unsigned short* fa0 = featfrag + ((size_t)(r * 2 + 0) * 128) * 512 + (size_t)lane * 8;
  const unsigned short* fa1 = featfrag + ((size_t)(r * 2 + 1) * 128) * 512 + (size_t)lane * 8;

  f32x4 acc00 = {0.f,0.f,0.f,0.f}, acc01 = acc00, acc10 = acc00, acc11 = acc00;

  auto stageW = [&](unsigned s, unsigned b) {
#pragma unroll
    for (int l = 0; l < 4; ++l) {
      const float* gp = gbase + (size_t)(s * 256 + l * 8) * D_IN;
      gload_lds16(gp, mytile + b * 1024 + l * 256);
    }
  };
  auto loadA = [&](unsigned s, bf16x8& A0, bf16x8& A1) {
    unsigned kt = s * 8 + w;
    A0 = *(const bf16x8*)(fa0 + (size_t)kt * 512);
    A1 = *(const bf16x8*)(fa1 + (size_t)kt * 512);
  };

  bf16x8 aC0, aC1, aN0, aN1, aF0, aF1;
  loadA(0, aC0, aC1);
  stageW(0, 0);
  loadA(1, aN0, aN1);
  stageW(1, 1);

  unsigned buf = 0;
#pragma unroll
  for (int s = 0; s < 16; ++s) {
    if (s < 14) {
      loadA(s + 2, aF0, aF1);                   // 2 vmem
      stageW(s + 2, (s + 2) % 3);               // 4 vmem
      asm volatile("s_waitcnt vmcnt(12)" ::: "memory"); // retire A(s)+stage(s)
    } else if (s == 14) {
      asm volatile("s_waitcnt vmcnt(6)" ::: "memory");  // retire through stage(14)
    } else {
      asm volatile("s_waitcnt vmcnt(0)" ::: "memory");
    }
    const float* tb = mytile + buf * 1024 + g * 8 * 32 + col;
    bf16x8 b0, b1;
#pragma unroll
    for (int j = 0; j < 8; ++j) {
      b0[j] = (short)f2bf(tb[j * 32]);
      b1[j] = (short)f2bf(tb[j * 32 + 16]);
    }
    acc00 = MFMA16(aC0, b0, acc00, 0, 0, 0);
    acc01 = MFMA16(aC0, b1, acc01, 0, 0, 0);
    acc10 = MFMA16(aC1, b0, acc10, 0, 0, 0);
    acc11 = MFMA16(aC1, b1, acc11, 0, 0, 0);
    aC0 = aN0; aC1 = aN1; aN0 = aF0; aN1 = aF1;
    buf = (buf + 1) % 3;
  }

  __syncthreads();                              // tiles dead; smem becomes red
  float* red = smem;                            // [7][4][64][4] = 28 KiB
  if (w > 0) {
#pragma unroll
    for (int i = 0; i < 4; ++i) {
      red[(((w - 1) * 4 + 0) * 64 + lane) * 4 + i] = acc00[i];
      red[(((w - 1) * 4 + 1) * 64 + lane) * 4 + i] = acc01[i];
      red[(((w - 1) * 4 + 2) * 64 + lane) * 4 + i] = acc10[i];
      red[(((w - 1) * 4 + 3) * 64 + lane) * 4 + i] = acc11[i];
    }
  }
  __syncthreads();
  if (w == 0) {
    for (int q = 0; q < 7; ++q)
#pragma unroll
      for (int i = 0; i < 4; ++i) {
        acc00[i] += red[((q * 4 + 0) * 64 + lane) * 4 + i];
        acc01[i] += red[((q * 4 + 1) * 64 + lane) * 4 + i];
        acc10[i] += red[((q * 4 + 2) * 64 + lane) * 4 + i];
        acc11[i] += red[((q * 4 + 3) * 64 + lane) * 4 + i];
      }
    float b0 = bdec[n0 + col], b1 = bdec[n0 + 16 + col];
#pragma unroll
    for (int i = 0; i < 4; ++i) {
      unsigned row0 = r * RS + g * 4 + i;
      unsigned row1 = row0 + 16;
      out[(size_t)row0 * D_IN + n0 + col]      = acc00[i] + b0;
      out[(size_t)row0 * D_IN + n0 + 16 + col] = acc01[i] + b1;
      out[(size_t)row1 * D_IN + n0 + col]      = acc10[i] + b0;
      out[(size_t)row1 * D_IN + n0 + 16 + col] = acc11[i] + b1;
    }
  }
}

// ---------------------------------------------------------------------------
extern "C" void kernel_launch(void* const* d_in, const int* in_sizes, int n_in,
                              void* d_out, int out_size, void* d_ws, size_t ws_size,
                              hipStream_t stream) {
  const float* acts = (const float*)d_in[0];
  const float* Wenc = (const float*)d_in[1];
  const float* benc = (const float*)d_in[2];
  const float* bdec = (const float*)d_in[3];
  const float* pos  = (const float*)d_in[4];
  const float* lnw  = (const float*)d_in[5];
  const float* lnb  = (const float*)d_in[6];
  const float* Wdec = (const float*)d_in[7];
  float* out = (float*)d_out;

  char* ws = (char*)d_ws;
  unsigned short* xfrag   = (unsigned short*)ws;                          // 512 KiB
  unsigned short* pre     = (unsigned short*)(ws + 512 * 1024);           // 1 MiB (bf16)
  unsigned short* featfrg = (unsigned short*)(ws + 1536 * 1024);          // 1 MiB

  prep_kernel  <<<128, 256, 0, stream>>>(acts, pos, bdec, xfrag);
  enc_kernel   <<<256, 256, 0, stream>>>(xfrag, Wenc, pre);
  lnpack_kernel<<<128, 256, 0, stream>>>(pre, benc, lnw, lnb, featfrg);
  dec_kernel   <<<256, 512, 0, stream>>>(featfrg, Wdec, bdec, out);
}